// Round 9
// baseline (160.685 us; speedup 1.0000x reference)
//
#include <hip/hip_runtime.h>
#include <hip/hip_bf16.h>
#include <cstdint>

#define B_ 16
#define C_ 112
#define HEADS_ 4
#define HD_ 28
#define NWIN_ 256
#define TOPK_ 128
#define D3_ 336
#define SCALE_ 0.18898223650461363f

typedef __attribute__((ext_vector_type(4))) float f32x4;
typedef __attribute__((ext_vector_type(8))) short short8;
typedef unsigned uint4u __attribute__((ext_vector_type(4), aligned(4)));  // dword-aligned 16B load

union Frag { unsigned u[4]; uint4 u4; short8 s; };

__device__ inline unsigned cvtpk(float a, float b) {
    unsigned r;
    asm("v_cvt_pk_bf16_f32 %0, %1, %2" : "=v"(r) : "v"(a), "v"(b));
    return r;   // lo16 = bf16(a), hi16 = bf16(b)
}
__device__ inline float bflo(unsigned u) { return __uint_as_float(u << 16); }
__device__ inline float bfhi(unsigned u) { return __uint_as_float(u & 0xFFFF0000u); }

// ---- kernel 0: build W fragments ----
__global__ __launch_bounds__(256) void wt_kernel(const float* __restrict__ W, const float* __restrict__ Wp,
                                                 uint4* __restrict__ WAq,
                                                 uint4* __restrict__ WAh, uint4* __restrict__ WAl) {
    const int id = blockIdx.x * 256 + threadIdx.x;
    if (id < 5376) {                       // 4*21*64
        const int ks = id / 1344, rem = id % 1344;
        const int tile = rem >> 6, l = rem & 63;
        const int d = tile * 16 + (l & 15);
        const int cb = ks * 32 + (l >> 4) * 8;
        float v[8];
        #pragma unroll
        for (int j = 0; j < 8; ++j) { int c = cb + j; v[j] = (c < C_) ? W[d * C_ + c] : 0.f; }
        uint4 o;
        o.x = cvtpk(v[0], v[1]); o.y = cvtpk(v[2], v[3]);
        o.z = cvtpk(v[4], v[5]); o.w = cvtpk(v[6], v[7]);
        WAq[id] = o;
    } else if (id < 5376 + 1792) {         // 4*7*64
        const int id2 = id - 5376;
        const int ks = id2 / 448, rem = id2 % 448;
        const int tile = rem >> 6, l = rem & 63;
        const int d = tile * 16 + (l & 15);
        const int cb = ks * 32 + (l >> 4) * 8;
        float v[8];
        #pragma unroll
        for (int j = 0; j < 8; ++j) { int c = cb + j; v[j] = (c < C_) ? Wp[d * C_ + c] : 0.f; }
        unsigned hw_[4], lw_[4];
        #pragma unroll
        for (int p = 0; p < 4; ++p) {
            unsigned hh = cvtpk(v[2 * p], v[2 * p + 1]);
            hw_[p] = hh;
            lw_[p] = cvtpk(v[2 * p] - bflo(hh), v[2 * p + 1] - bfhi(hh));
        }
        WAh[id2] = make_uint4(hw_[0], hw_[1], hw_[2], hw_[3]);
        WAl[id2] = make_uint4(lw_[0], lw_[1], lw_[2], lw_[3]);
    }
}

// ---- kernel 1: qkv_bf[b][hw][336] (bf16) = x @ Wqkv^T via MFMA ----
// stage x once; B-frags in registers; loop all 3 d-blocks in-kernel.
__global__ __launch_bounds__(256) void qkv_kernel(const float* __restrict__ x,
                                                  const uint4* __restrict__ WAq,
                                                  ushort* __restrict__ qkv) {
    __shared__ unsigned xs[64][132];   // bf16 pairs [c2][hw]
    const int hw0 = blockIdx.x << 7;
    const int b = blockIdx.y;
    const int tid = threadIdx.x;
    for (int i = tid; i < 2048; i += 256) {
        const int c2 = i >> 5, j4 = (i & 31) << 2;
        uint4 o = make_uint4(0, 0, 0, 0);
        if (c2 < 56) {
            const float* r0 = x + (((size_t)b * C_ + 2 * c2) << 12) + hw0 + j4;
            float4 a = *(const float4*)r0;
            float4 c = *(const float4*)(r0 + 4096);
            o.x = cvtpk(a.x, c.x); o.y = cvtpk(a.y, c.y);
            o.z = cvtpk(a.z, c.z); o.w = cvtpk(a.w, c.w);
        }
        *(uint4*)&xs[c2][j4] = o;
    }
    __syncthreads();
    const int wv = tid >> 6, l = tid & 63, lq = l & 15, g = l >> 4;
    const int hwl = wv << 5;
    // B-fragments once, reused for all 3 d-blocks
    Frag bf[4][2];
    #pragma unroll
    for (int ks = 0; ks < 4; ++ks)
        #pragma unroll
        for (int n = 0; n < 2; ++n) {
            const int col = hwl + (n << 4) + lq;
            const int r0 = (ks << 4) + (g << 2);
            bf[ks][n].u[0] = xs[r0][col]; bf[ks][n].u[1] = xs[r0 + 1][col];
            bf[ks][n].u[2] = xs[r0 + 2][col]; bf[ks][n].u[3] = xs[r0 + 3][col];
        }
    const size_t hwbase = ((size_t)b << 12) + hw0;
    #pragma unroll
    for (int dblk = 0; dblk < 3; ++dblk) {
        f32x4 acc[7][2] = {};
        #pragma unroll
        for (int ks = 0; ks < 4; ++ks) {
            const uint4* wp = WAq + ((ks * 21 + dblk * 7) << 6) + l;
            #pragma unroll
            for (int m = 0; m < 7; ++m) {
                Frag af; af.u4 = wp[m << 6];
                acc[m][0] = __builtin_amdgcn_mfma_f32_16x16x32_bf16(af.s, bf[ks][0].s, acc[m][0], 0, 0, 0);
                acc[m][1] = __builtin_amdgcn_mfma_f32_16x16x32_bf16(af.s, bf[ks][1].s, acc[m][1], 0, 0, 0);
            }
        }
        #pragma unroll
        for (int m = 0; m < 7; ++m) {
            const int d0 = dblk * 112 + (m << 4) + (g << 2);
            #pragma unroll
            for (int n = 0; n < 2; ++n) {
                const int hw = hwl + (n << 4) + lq;
                uint2 o2;
                o2.x = cvtpk(acc[m][n][0], acc[m][n][1]);
                o2.y = cvtpk(acc[m][n][2], acc[m][n][3]);
                *(uint2*)(qkv + (hwbase + hw) * D3_ + d0) = o2;
            }
        }
    }
}

// ---- kernel 2: fused windowed top-k attention + output projection ----
__global__ __launch_bounds__(256) void attn_kernel(const ushort* __restrict__ qkv,
                                                   const int* __restrict__ topk,
                                                   const uint4* __restrict__ WAh,
                                                   const uint4* __restrict__ WAl,
                                                   const float* __restrict__ bp,
                                                   float* __restrict__ out) {
    __shared__ int idxs[TOPK_];
    __shared__ __align__(16) unsigned vsT[4][32][68];   // per-wave V^T bf16 pairs [d][k/2]
    __shared__ __align__(16) unsigned plds[4][16][68];  // per-wave P [q][k/2]; aliased as os[128][17] fp32 in proj
    // XCD-aware swizzle: each XCD sweeps one batch over a contiguous window strip
    const int bid = blockIdx.x;
    const int xcd = bid & 7, j = bid >> 3;
    const int b = j >> 5;
    const int w = (xcd << 5) | (j & 31);
    const int wy = w >> 4, wx = w & 15;
    const int tid = threadIdx.x;
    const int wv = tid >> 6, l = tid & 63, lq = l & 15, g = l >> 4;
    if (tid < TOPK_) idxs[tid] = topk[w * TOPK_ + tid];
    __syncthreads();
    const int h = wv;
    const size_t bbase = (size_t)(b << 12);
    const int hwq = ((wy * 4 + (lq >> 2)) << 6) + (wx << 2) + (lq & 3);
    // Q fragment (B operand), scale folded into scores
    Frag qf;
    {
        uint4u t = *(const uint4u*)(qkv + (bbase + hwq) * D3_ + h * HD_ + (g << 3));
        qf.u[0] = t[0]; qf.u[1] = t[1];
        qf.u[2] = (g == 3) ? 0u : t[2];
        qf.u[3] = (g == 3) ? 0u : t[3];
    }
    // K fragments (A operand)
    Frag kf[8];
    #pragma unroll
    for (int m = 0; m < 8; ++m) {
        const int kr = idxs[(m << 4) + lq];
        uint4u t = *(const uint4u*)(qkv + (bbase + kr) * D3_ + C_ + h * HD_ + (g << 3));
        kf[m].u[0] = t[0]; kf[m].u[1] = t[1]; kf[m].u[2] = t[2]; kf[m].u[3] = t[3];
    }
    // prefetch Wproj fragments for the fused projection (hide under attn compute)
    Frag wah[2][4], wal[2][4];
    #pragma unroll
    for (int mi = 0; mi < 2; ++mi) {
        const int m = (wv << 1) + mi;
        #pragma unroll
        for (int ks = 0; ks < 4; ++ks) {
            if (m < 7) {
                wah[mi][ks].u4 = WAh[((ks * 7 + m) << 6) + l];
                wal[mi][ks].u4 = WAl[((ks * 7 + m) << 6) + l];
            } else {
                wah[mi][ks].u4 = make_uint4(0, 0, 0, 0);
                wal[mi][ks].u4 = make_uint4(0, 0, 0, 0);
            }
        }
    }
    // V gather rows 2l, 2l+1 -> transpose-pack via v_perm
    {
        const ushort* v0 = qkv + (bbase + idxs[2 * l]) * D3_ + 2 * C_ + h * HD_;
        const ushort* v1 = qkv + (bbase + idxs[2 * l + 1]) * D3_ + 2 * C_ + h * HD_;
        unsigned w0[14], w1[14];
        { uint4u a = *(const uint4u*)v0;        w0[0]=a[0]; w0[1]=a[1]; w0[2]=a[2]; w0[3]=a[3]; }
        { uint4u a = *(const uint4u*)(v0 + 8);  w0[4]=a[0]; w0[5]=a[1]; w0[6]=a[2]; w0[7]=a[3]; }
        { uint4u a = *(const uint4u*)(v0 + 16); w0[8]=a[0]; w0[9]=a[1]; w0[10]=a[2]; w0[11]=a[3]; }
        { uint2 a = *(const uint2*)(v0 + 24);   w0[12]=a.x; w0[13]=a.y; }
        { uint4u a = *(const uint4u*)v1;        w1[0]=a[0]; w1[1]=a[1]; w1[2]=a[2]; w1[3]=a[3]; }
        { uint4u a = *(const uint4u*)(v1 + 8);  w1[4]=a[0]; w1[5]=a[1]; w1[6]=a[2]; w1[7]=a[3]; }
        { uint4u a = *(const uint4u*)(v1 + 16); w1[8]=a[0]; w1[9]=a[1]; w1[10]=a[2]; w1[11]=a[3]; }
        { uint2 a = *(const uint2*)(v1 + 24);   w1[12]=a.x; w1[13]=a.y; }
        #pragma unroll
        for (int jj = 0; jj < 14; ++jj) {
            vsT[wv][2 * jj][l]     = __builtin_amdgcn_perm(w1[jj], w0[jj], 0x05040100);
            vsT[wv][2 * jj + 1][l] = __builtin_amdgcn_perm(w1[jj], w0[jj], 0x07060302);
        }
    }
    // QK^T -> S^T[k][q]
    f32x4 sacc[8];
    #pragma unroll
    for (int m = 0; m < 8; ++m) {
        f32x4 z = {0.f, 0.f, 0.f, 0.f};
        sacc[m] = __builtin_amdgcn_mfma_f32_16x16x32_bf16(kf[m].s, qf.s, z, 0, 0, 0);
    }
    // scale + softmax over k (in-register, xor16/32)
    float mx = -1e30f;
    #pragma unroll
    for (int m = 0; m < 8; ++m)
        #pragma unroll
        for (int r = 0; r < 4; ++r) { sacc[m][r] *= SCALE_; mx = fmaxf(mx, sacc[m][r]); }
    mx = fmaxf(mx, __shfl_xor(mx, 16, 64));
    mx = fmaxf(mx, __shfl_xor(mx, 32, 64));
    float sum = 0.f;
    #pragma unroll
    for (int m = 0; m < 8; ++m)
        #pragma unroll
        for (int r = 0; r < 4; ++r) { float e = __expf(sacc[m][r] - mx); sacc[m][r] = e; sum += e; }
    sum += __shfl_xor(sum, 16, 64);
    sum += __shfl_xor(sum, 32, 64);
    const float inv = 1.f / sum;
    #pragma unroll
    for (int m = 0; m < 8; ++m) {
        unsigned u0 = cvtpk(sacc[m][0] * inv, sacc[m][1] * inv);
        unsigned u1 = cvtpk(sacc[m][2] * inv, sacc[m][3] * inv);
        *(uint2*)&plds[wv][lq][(m << 3) + (g << 1)] = make_uint2(u0, u1);
    }
    // PV: O^T[d][q]
    f32x4 oacc[2] = {};
    #pragma unroll
    for (int ks = 0; ks < 4; ++ks) {
        Frag pb;
        pb.u4 = *(const uint4*)&plds[wv][lq][(g << 2) + (ks << 4)];
        #pragma unroll
        for (int m = 0; m < 2; ++m) {
            Frag va;
            va.u4 = *(const uint4*)&vsT[wv][lq + (m << 4)][(g << 2) + (ks << 4)];
            oacc[m] = __builtin_amdgcn_mfma_f32_16x16x32_bf16(va.s, pb.s, oacc[m], 0, 0, 0);
        }
    }
    // ================= fused projection =================
    __syncthreads();   // all waves done reading plds/vsT
    float* os = (float*)&plds[0][0][0];   // os[c][q], stride 17; c = h*28+d
    for (int i = 1904 + tid; i < 2176; i += 256) os[i] = 0.f;   // zero pad rows c=112..127
    #pragma unroll
    for (int m = 0; m < 2; ++m) {
        const int d0 = (g << 2) + (m << 4);
        if (d0 < HD_) {
            #pragma unroll
            for (int r = 0; r < 4; ++r)
                os[(h * HD_ + d0 + r) * 17 + lq] = oacc[m][r];
        }
    }
    __syncthreads();
    // out[d][hw] = Wp[d][:] . O[hw][:] + bias ; wave wv handles d-tiles m = 2wv, 2wv+1
    f32x4 pacc[2] = {};
    #pragma unroll
    for (int ks = 0; ks < 4; ++ks) {
        const int cb = (g << 3) + (ks << 5);
        float v[8];
        #pragma unroll
        for (int jj = 0; jj < 8; ++jj) v[jj] = os[(cb + jj) * 17 + lq];
        Frag bh, bl;
        #pragma unroll
        for (int p = 0; p < 4; ++p) {
            unsigned hh = cvtpk(v[2 * p], v[2 * p + 1]);
            bh.u[p] = hh;
            bl.u[p] = cvtpk(v[2 * p] - bflo(hh), v[2 * p + 1] - bfhi(hh));
        }
        #pragma unroll
        for (int mi = 0; mi < 2; ++mi) {
            pacc[mi] = __builtin_amdgcn_mfma_f32_16x16x32_bf16(wah[mi][ks].s, bh.s, pacc[mi], 0, 0, 0);
            pacc[mi] = __builtin_amdgcn_mfma_f32_16x16x32_bf16(wah[mi][ks].s, bl.s, pacc[mi], 0, 0, 0);
            pacc[mi] = __builtin_amdgcn_mfma_f32_16x16x32_bf16(wal[mi][ks].s, bh.s, pacc[mi], 0, 0, 0);
        }
    }
    #pragma unroll
    for (int mi = 0; mi < 2; ++mi) {
        const int m = (wv << 1) + mi;
        if (m < 7) {
            const int d0 = (m << 4) + (g << 2);
            const float4 bias = *(const float4*)(bp + d0);
            out[(((size_t)(b * C_ + d0 + 0)) << 12) + hwq] = pacc[mi][0] + bias.x;
            out[(((size_t)(b * C_ + d0 + 1)) << 12) + hwq] = pacc[mi][1] + bias.y;
            out[(((size_t)(b * C_ + d0 + 2)) << 12) + hwq] = pacc[mi][2] + bias.z;
            out[(((size_t)(b * C_ + d0 + 3)) << 12) + hwq] = pacc[mi][3] + bias.w;
        }
    }
}

extern "C" void kernel_launch(void* const* d_in, const int* in_sizes, int n_in,
                              void* d_out, int out_size, void* d_ws, size_t ws_size,
                              hipStream_t stream) {
    const float* x     = (const float*)d_in[0];
    const float* Wqkv  = (const float*)d_in[1];
    const float* Wproj = (const float*)d_in[2];
    const float* bproj = (const float*)d_in[3];
    const int*   topk  = (const int*)d_in[4];
    float* out = (float*)d_out;
    char* ws = (char*)d_ws;
    ushort* qkv = (ushort*)ws;                         // 44,040,192 B (bf16 [16][4096][336])
    uint4*  WAq = (uint4*)(ws + 44040192);             //     86,016 B
    uint4*  WAh = (uint4*)(ws + 44040192 + 86016);     //     28,672 B
    uint4*  WAl = (uint4*)(ws + 44040192 + 86016 + 28672);
    wt_kernel<<<28, 256, 0, stream>>>(Wqkv, Wproj, WAq, WAh, WAl);
    qkv_kernel<<<dim3(32, 16), 256, 0, stream>>>(x, WAq, qkv);
    attn_kernel<<<dim3(NWIN_ * B_), 256, 0, stream>>>(qkv, topk, WAh, WAl, bproj, out);
}

// Round 10
// 146.468 us; speedup vs baseline: 1.0971x; 1.0971x over previous
//
#include <hip/hip_runtime.h>
#include <hip/hip_bf16.h>
#include <cstdint>

#define B_ 16
#define C_ 112
#define HEADS_ 4
#define HD_ 28
#define NWIN_ 256
#define TOPK_ 128
#define D3_ 336
#define SCALE_ 0.18898223650461363f

typedef __attribute__((ext_vector_type(4))) float f32x4;
typedef __attribute__((ext_vector_type(8))) short short8;
typedef unsigned uint4u __attribute__((ext_vector_type(4), aligned(4)));  // dword-aligned 16B load

union Frag { unsigned u[4]; uint4 u4; short8 s; };

__device__ inline unsigned cvtpk(float a, float b) {
    unsigned r;
    asm("v_cvt_pk_bf16_f32 %0, %1, %2" : "=v"(r) : "v"(a), "v"(b));
    return r;   // lo16 = bf16(a), hi16 = bf16(b)
}
__device__ inline float bflo(unsigned u) { return __uint_as_float(u << 16); }
__device__ inline float bfhi(unsigned u) { return __uint_as_float(u & 0xFFFF0000u); }

// ---- kernel 0: build W fragments ----
__global__ __launch_bounds__(256) void wt_kernel(const float* __restrict__ W, const float* __restrict__ Wp,
                                                 uint4* __restrict__ WAq,
                                                 uint4* __restrict__ WAh, uint4* __restrict__ WAl) {
    const int id = blockIdx.x * 256 + threadIdx.x;
    if (id < 5376) {                       // 4*21*64
        const int ks = id / 1344, rem = id % 1344;
        const int tile = rem >> 6, l = rem & 63;
        const int d = tile * 16 + (l & 15);
        const int cb = ks * 32 + (l >> 4) * 8;
        float v[8];
        #pragma unroll
        for (int j = 0; j < 8; ++j) { int c = cb + j; v[j] = (c < C_) ? W[d * C_ + c] : 0.f; }
        uint4 o;
        o.x = cvtpk(v[0], v[1]); o.y = cvtpk(v[2], v[3]);
        o.z = cvtpk(v[4], v[5]); o.w = cvtpk(v[6], v[7]);
        WAq[id] = o;
    } else if (id < 5376 + 1792) {         // 4*7*64
        const int id2 = id - 5376;
        const int ks = id2 / 448, rem = id2 % 448;
        const int tile = rem >> 6, l = rem & 63;
        const int d = tile * 16 + (l & 15);
        const int cb = ks * 32 + (l >> 4) * 8;
        float v[8];
        #pragma unroll
        for (int j = 0; j < 8; ++j) { int c = cb + j; v[j] = (c < C_) ? Wp[d * C_ + c] : 0.f; }
        unsigned hw_[4], lw_[4];
        #pragma unroll
        for (int p = 0; p < 4; ++p) {
            unsigned hh = cvtpk(v[2 * p], v[2 * p + 1]);
            hw_[p] = hh;
            lw_[p] = cvtpk(v[2 * p] - bflo(hh), v[2 * p + 1] - bfhi(hh));
        }
        WAh[id2] = make_uint4(hw_[0], hw_[1], hw_[2], hw_[3]);
        WAl[id2] = make_uint4(lw_[0], lw_[1], lw_[2], lw_[3]);
    }
}

// ---- kernel 1: qkv_bf[b][hw][336] (bf16) = x @ Wqkv^T via MFMA (round-8 proven form) ----
__global__ __launch_bounds__(256) void qkv_kernel(const float* __restrict__ x,
                                                  const uint4* __restrict__ WAq,
                                                  ushort* __restrict__ qkv) {
    __shared__ unsigned xs[64][132];   // bf16 pairs [c2][hw]
    const int hw0 = blockIdx.x << 7;
    const int dblk = blockIdx.y;       // 0..2
    const int b = blockIdx.z;
    const int tid = threadIdx.x;
    for (int i = tid; i < 2048; i += 256) {
        const int c2 = i >> 5, j4 = (i & 31) << 2;
        uint4 o = make_uint4(0, 0, 0, 0);
        if (c2 < 56) {
            const float* r0 = x + (((size_t)b * C_ + 2 * c2) << 12) + hw0 + j4;
            float4 a = *(const float4*)r0;
            float4 c = *(const float4*)(r0 + 4096);
            o.x = cvtpk(a.x, c.x); o.y = cvtpk(a.y, c.y);
            o.z = cvtpk(a.z, c.z); o.w = cvtpk(a.w, c.w);
        }
        *(uint4*)&xs[c2][j4] = o;
    }
    __syncthreads();
    const int wv = tid >> 6, l = tid & 63, lq = l & 15, g = l >> 4;
    const int hwl = wv << 5;
    f32x4 acc[7][2] = {};
    #pragma unroll
    for (int ks = 0; ks < 4; ++ks) {
        Frag bf[2];
        #pragma unroll
        for (int n = 0; n < 2; ++n) {
            const int col = hwl + (n << 4) + lq;
            const int r0 = (ks << 4) + (g << 2);
            bf[n].u[0] = xs[r0][col]; bf[n].u[1] = xs[r0 + 1][col];
            bf[n].u[2] = xs[r0 + 2][col]; bf[n].u[3] = xs[r0 + 3][col];
        }
        const uint4* wp = WAq + ((ks * 21 + dblk * 7) << 6) + l;
        #pragma unroll
        for (int m = 0; m < 7; ++m) {
            Frag af; af.u4 = wp[m << 6];
            acc[m][0] = __builtin_amdgcn_mfma_f32_16x16x32_bf16(af.s, bf[0].s, acc[m][0], 0, 0, 0);
            acc[m][1] = __builtin_amdgcn_mfma_f32_16x16x32_bf16(af.s, bf[1].s, acc[m][1], 0, 0, 0);
        }
    }
    const size_t hwbase = ((size_t)b << 12) + hw0;
    #pragma unroll
    for (int m = 0; m < 7; ++m) {
        const int d0 = dblk * 112 + (m << 4) + (g << 2);
        #pragma unroll
        for (int n = 0; n < 2; ++n) {
            const int hw = hwl + (n << 4) + lq;
            uint2 o2;
            o2.x = cvtpk(acc[m][n][0], acc[m][n][1]);
            o2.y = cvtpk(acc[m][n][2], acc[m][n][3]);
            *(uint2*)(qkv + (hwbase + hw) * D3_ + d0) = o2;
        }
    }
}

// ---- kernel 2: fused windowed top-k attention + output projection ----
// no idxs barrier (direct topk loads); V-pack sunk below softmax to hide gather latency.
__global__ __launch_bounds__(256, 3) void attn_kernel(const ushort* __restrict__ qkv,
                                                      const int* __restrict__ topk,
                                                      const uint4* __restrict__ WAh,
                                                      const uint4* __restrict__ WAl,
                                                      const float* __restrict__ bp,
                                                      float* __restrict__ out) {
    __shared__ __align__(16) unsigned vsT[4][32][68];   // per-wave V^T bf16 pairs [d][k/2]
    __shared__ __align__(16) unsigned plds[4][16][68];  // per-wave P [q][k/2]; aliased as os[128][17] fp32 in proj
    // XCD-aware swizzle: each XCD sweeps one batch over a contiguous window strip
    const int bid = blockIdx.x;
    const int xcd = bid & 7, j = bid >> 3;
    const int b = j >> 5;
    const int w = (xcd << 5) | (j & 31);
    const int wy = w >> 4, wx = w & 15;
    const int tid = threadIdx.x;
    const int wv = tid >> 6, l = tid & 63, lq = l & 15, g = l >> 4;
    const int h = wv;
    const size_t bbase = (size_t)(b << 12);
    const int hwq = ((wy * 4 + (lq >> 2)) << 6) + (wx << 2) + (lq & 3);
    const int* tkw = topk + (w << 7);
    // ---- issue all global loads up front ----
    // Q fragment (B operand), scale folded into scores
    Frag qf;
    {
        uint4u t = *(const uint4u*)(qkv + (bbase + hwq) * D3_ + h * HD_ + (g << 3));
        qf.u[0] = t[0]; qf.u[1] = t[1];
        qf.u[2] = (g == 3) ? 0u : t[2];
        qf.u[3] = (g == 3) ? 0u : t[3];
    }
    // K fragments (A operand), idx direct from topk (L1-hot)
    Frag kf[8];
    #pragma unroll
    for (int m = 0; m < 8; ++m) {
        const int kr = tkw[(m << 4) + lq];
        uint4u t = *(const uint4u*)(qkv + (bbase + kr) * D3_ + C_ + h * HD_ + (g << 3));
        kf[m].u[0] = t[0]; kf[m].u[1] = t[1]; kf[m].u[2] = t[2]; kf[m].u[3] = t[3];
    }
    // V rows 2l, 2l+1 into registers (packed later, after softmax)
    unsigned w0[14], w1[14];
    {
        const int2 vidx = *(const int2*)(tkw + 2 * l);
        const ushort* v0 = qkv + (bbase + vidx.x) * D3_ + 2 * C_ + h * HD_;
        const ushort* v1 = qkv + (bbase + vidx.y) * D3_ + 2 * C_ + h * HD_;
        { uint4u a = *(const uint4u*)v0;        w0[0]=a[0]; w0[1]=a[1]; w0[2]=a[2]; w0[3]=a[3]; }
        { uint4u a = *(const uint4u*)(v0 + 8);  w0[4]=a[0]; w0[5]=a[1]; w0[6]=a[2]; w0[7]=a[3]; }
        { uint4u a = *(const uint4u*)(v0 + 16); w0[8]=a[0]; w0[9]=a[1]; w0[10]=a[2]; w0[11]=a[3]; }
        { uint2 a = *(const uint2*)(v0 + 24);   w0[12]=a.x; w0[13]=a.y; }
        { uint4u a = *(const uint4u*)v1;        w1[0]=a[0]; w1[1]=a[1]; w1[2]=a[2]; w1[3]=a[3]; }
        { uint4u a = *(const uint4u*)(v1 + 8);  w1[4]=a[0]; w1[5]=a[1]; w1[6]=a[2]; w1[7]=a[3]; }
        { uint4u a = *(const uint4u*)(v1 + 16); w1[8]=a[0]; w1[9]=a[1]; w1[10]=a[2]; w1[11]=a[3]; }
        { uint2 a = *(const uint2*)(v1 + 24);   w1[12]=a.x; w1[13]=a.y; }
    }
    // Wproj fragment prefetch (L2-hot, consumed in proj tail)
    Frag wah[2][4], wal[2][4];
    #pragma unroll
    for (int mi = 0; mi < 2; ++mi) {
        const int m = (wv << 1) + mi;
        #pragma unroll
        for (int ks = 0; ks < 4; ++ks) {
            if (m < 7) {
                wah[mi][ks].u4 = WAh[((ks * 7 + m) << 6) + l];
                wal[mi][ks].u4 = WAl[((ks * 7 + m) << 6) + l];
            } else {
                wah[mi][ks].u4 = make_uint4(0, 0, 0, 0);
                wal[mi][ks].u4 = make_uint4(0, 0, 0, 0);
            }
        }
    }
    // ---- QK^T -> S^T[k][q] (needs only K,Q; V still in flight is fine) ----
    f32x4 sacc[8];
    #pragma unroll
    for (int m = 0; m < 8; ++m) {
        f32x4 z = {0.f, 0.f, 0.f, 0.f};
        sacc[m] = __builtin_amdgcn_mfma_f32_16x16x32_bf16(kf[m].s, qf.s, z, 0, 0, 0);
    }
    // ---- scale + softmax over k (in-register, xor16/32) ----
    float mx = -1e30f;
    #pragma unroll
    for (int m = 0; m < 8; ++m)
        #pragma unroll
        for (int r = 0; r < 4; ++r) { sacc[m][r] *= SCALE_; mx = fmaxf(mx, sacc[m][r]); }
    mx = fmaxf(mx, __shfl_xor(mx, 16, 64));
    mx = fmaxf(mx, __shfl_xor(mx, 32, 64));
    float sum = 0.f;
    #pragma unroll
    for (int m = 0; m < 8; ++m)
        #pragma unroll
        for (int r = 0; r < 4; ++r) { float e = __expf(sacc[m][r] - mx); sacc[m][r] = e; sum += e; }
    sum += __shfl_xor(sum, 16, 64);
    sum += __shfl_xor(sum, 32, 64);
    const float inv = 1.f / sum;
    // ---- P -> plds (own-wave region, no barrier needed) ----
    #pragma unroll
    for (int m = 0; m < 8; ++m) {
        unsigned u0 = cvtpk(sacc[m][0] * inv, sacc[m][1] * inv);
        unsigned u1 = cvtpk(sacc[m][2] * inv, sacc[m][3] * inv);
        *(uint2*)&plds[wv][lq][(m << 3) + (g << 1)] = make_uint2(u0, u1);
    }
    // ---- V transpose-pack via v_perm (sunk here: global latency hidden under QK^T+softmax) ----
    #pragma unroll
    for (int jj = 0; jj < 14; ++jj) {
        vsT[wv][2 * jj][l]     = __builtin_amdgcn_perm(w1[jj], w0[jj], 0x05040100);
        vsT[wv][2 * jj + 1][l] = __builtin_amdgcn_perm(w1[jj], w0[jj], 0x07060302);
    }
    // ---- PV: O^T[d][q] (reads own-wave plds/vsT; lgkmcnt ordering suffices) ----
    f32x4 oacc[2] = {};
    #pragma unroll
    for (int ks = 0; ks < 4; ++ks) {
        Frag pb;
        pb.u4 = *(const uint4*)&plds[wv][lq][(g << 2) + (ks << 4)];
        #pragma unroll
        for (int m = 0; m < 2; ++m) {
            Frag va;
            va.u4 = *(const uint4*)&vsT[wv][lq + (m << 4)][(g << 2) + (ks << 4)];
            oacc[m] = __builtin_amdgcn_mfma_f32_16x16x32_bf16(va.s, pb.s, oacc[m], 0, 0, 0);
        }
    }
    // ================= fused projection =================
    __syncthreads();   // all waves done with plds before aliasing as os
    float* os = (float*)&plds[0][0][0];   // os[c][q], stride 17; c = h*28+d
    for (int i = 1904 + tid; i < 2176; i += 256) os[i] = 0.f;   // zero pad rows c=112..127
    #pragma unroll
    for (int m = 0; m < 2; ++m) {
        const int d0 = (g << 2) + (m << 4);
        if (d0 < HD_) {
            #pragma unroll
            for (int r = 0; r < 4; ++r)
                os[(h * HD_ + d0 + r) * 17 + lq] = oacc[m][r];
        }
    }
    __syncthreads();
    // out[d][hw] = Wp[d][:] . O[hw][:] + bias ; wave wv handles d-tiles m = 2wv, 2wv+1
    f32x4 pacc[2] = {};
    #pragma unroll
    for (int ks = 0; ks < 4; ++ks) {
        const int cb = (g << 3) + (ks << 5);
        float v[8];
        #pragma unroll
        for (int jj = 0; jj < 8; ++jj) v[jj] = os[(cb + jj) * 17 + lq];
        Frag bh, bl;
        #pragma unroll
        for (int p = 0; p < 4; ++p) {
            unsigned hh = cvtpk(v[2 * p], v[2 * p + 1]);
            bh.u[p] = hh;
            bl.u[p] = cvtpk(v[2 * p] - bflo(hh), v[2 * p + 1] - bfhi(hh));
        }
        #pragma unroll
        for (int mi = 0; mi < 2; ++mi) {
            pacc[mi] = __builtin_amdgcn_mfma_f32_16x16x32_bf16(wah[mi][ks].s, bh.s, pacc[mi], 0, 0, 0);
            pacc[mi] = __builtin_amdgcn_mfma_f32_16x16x32_bf16(wah[mi][ks].s, bl.s, pacc[mi], 0, 0, 0);
            pacc[mi] = __builtin_amdgcn_mfma_f32_16x16x32_bf16(wal[mi][ks].s, bh.s, pacc[mi], 0, 0, 0);
        }
    }
    #pragma unroll
    for (int mi = 0; mi < 2; ++mi) {
        const int m = (wv << 1) + mi;
        if (m < 7) {
            const int d0 = (m << 4) + (g << 2);
            const float4 bias = *(const float4*)(bp + d0);
            out[(((size_t)(b * C_ + d0 + 0)) << 12) + hwq] = pacc[mi][0] + bias.x;
            out[(((size_t)(b * C_ + d0 + 1)) << 12) + hwq] = pacc[mi][1] + bias.y;
            out[(((size_t)(b * C_ + d0 + 2)) << 12) + hwq] = pacc[mi][2] + bias.z;
            out[(((size_t)(b * C_ + d0 + 3)) << 12) + hwq] = pacc[mi][3] + bias.w;
        }
    }
}

extern "C" void kernel_launch(void* const* d_in, const int* in_sizes, int n_in,
                              void* d_out, int out_size, void* d_ws, size_t ws_size,
                              hipStream_t stream) {
    const float* x     = (const float*)d_in[0];
    const float* Wqkv  = (const float*)d_in[1];
    const float* Wproj = (const float*)d_in[2];
    const float* bproj = (const float*)d_in[3];
    const int*   topk  = (const int*)d_in[4];
    float* out = (float*)d_out;
    char* ws = (char*)d_ws;
    ushort* qkv = (ushort*)ws;                         // 44,040,192 B (bf16 [16][4096][336])
    uint4*  WAq = (uint4*)(ws + 44040192);             //     86,016 B
    uint4*  WAh = (uint4*)(ws + 44040192 + 86016);     //     28,672 B
    uint4*  WAl = (uint4*)(ws + 44040192 + 86016 + 28672);
    wt_kernel<<<28, 256, 0, stream>>>(Wqkv, Wproj, WAq, WAh, WAl);
    qkv_kernel<<<dim3(32, 3, 16), 256, 0, stream>>>(x, WAq, qkv);
    attn_kernel<<<dim3(NWIN_ * B_), 256, 0, stream>>>(qkv, topk, WAh, WAl, bproj, out);
}